// Round 11
// baseline (1134.920 us; speedup 1.0000x reference)
//
#include <hip/hip_runtime.h>
#include <math.h>

#define PLANE 16384
#define NTOT  33554432u
#define TP    136            // LDS row pitch in shorts for T/P arrays
typedef unsigned int  uint;
typedef unsigned short ushort;

typedef __attribute__((ext_vector_type(8))) short  short8;
typedef __attribute__((ext_vector_type(8))) ushort ushort8;
typedef __attribute__((ext_vector_type(4))) ushort bf16x4;
typedef __attribute__((ext_vector_type(4))) uint   u32x4;
typedef __attribute__((ext_vector_type(4))) float  f32x4;

__device__ __forceinline__ ushort f2bf(float x){
  unsigned u = __float_as_uint(x);
  u = (u + 0x7FFFu + ((u >> 16) & 1u)) >> 16;
  return (ushort)u;
}
__device__ __forceinline__ float bf2f(ushort h){
  return __uint_as_float(((uint)h) << 16);
}
__device__ __forceinline__ uint pk(float a, float b){
  return (uint)f2bf(a) | ((uint)f2bf(b) << 16);
}
// split packed (re,im) bf16 dwords into two short8 fragments
__device__ __forceinline__ void unpack2(u32x4 a, u32x4 b, short8& re, short8& im){
  union { uint u[4]; short8 s; } R, I;
  R.u[0] = (a[0]&0xffffu) | (a[1]<<16);
  R.u[1] = (a[2]&0xffffu) | (a[3]<<16);
  R.u[2] = (b[0]&0xffffu) | (b[1]<<16);
  R.u[3] = (b[2]&0xffffu) | (b[3]<<16);
  I.u[0] = (a[0]>>16) | (a[1]&0xffff0000u);
  I.u[1] = (a[2]>>16) | (a[3]&0xffff0000u);
  I.u[2] = (b[0]>>16) | (b[1]&0xffff0000u);
  I.u[3] = (b[2]>>16) | (b[3]&0xffff0000u);
  re = R.s; im = I.s;
}
__device__ __forceinline__ short8 cvt8(f32x4 a, f32x4 b){
  union { ushort h[8]; short8 s; } r;
  #pragma unroll
  for(int j=0;j<4;j++){ r.h[j]=f2bf(a[j]); r.h[4+j]=f2bf(b[j]); }
  return r.s;
}
// apply sign mask (bf16 sign-bit flips) to a fragment
__device__ __forceinline__ short8 frg(short8 base, uint m){
  union { short8 s; u32x4 u; } x; x.s = base;
  x.u[0]^=m; x.u[1]^=m; x.u[2]^=m; x.u[3]^=m;
  return x.s;
}
#define W128 0.049087385212340517f   // 2*pi/128

// quarter twiddle table in registers: rows n=16a+c (a<4 -> n<64),
// k = kk*32 + 8q + j (kk<2 -> k<64). Extend via:
//   n>=64: *(-1)^k  -> XOR 0x80000000 (odd-j shorts)   [hiM]
//   k>=64: *(-1)^n  -> XOR 0x80008000 if c odd          [LM]
template<int SGN>
__device__ __forceinline__ void gen_quarter(short8 (&st_r)[4][2], short8 (&st_i)[4][2],
                                            int c, int q){
  #pragma unroll
  for(int a=0;a<4;a++){
    int n = 16*a + c;
    #pragma unroll
    for(int kk=0;kk<2;kk++){
      union{ushort h[8]; short8 s;} R, I;
      #pragma unroll
      for(int j=0;j<8;j++){
        int k = kk*32 + 8*q + j;
        float ss, cc; __sincosf((float)((n*k)&127)*W128, &ss, &cc);
        R.h[j] = f2bf(cc); I.h[j] = f2bf(SGN < 0 ? -ss : ss);
      }
      st_r[a][kk]=R.s; st_i[a][kk]=I.s;
    }
  }
}

// ---------------- kernel 0: fold BN, emit MFMA-fragment-packed bf16 weights --
__global__ __launch_bounds__(256) void k_prep(
    const float* __restrict__ w1, const float* __restrict__ b1,
    const float* __restrict__ g1, const float* __restrict__ be1,
    const float* __restrict__ m1, const float* __restrict__ v1,
    const float* __restrict__ w2, const float* __restrict__ b2,
    const float* __restrict__ g2, const float* __restrict__ be2,
    const float* __restrict__ m2, const float* __restrict__ v2,
    float* __restrict__ wb){
  int g = blockIdx.x*256 + threadIdx.x;      // 65536 threads
  ushort* wbs = (ushort*)wb;
  if(g < 32768){
    int kt = (g >> 9) & 3, l = (g >> 3) & 63, j = g & 7;
    int et = g >> 11;
    int c = kt*32 + 8*(l>>4) + j;
    int e = et*16 + (l&15);
    float s1 = g1[e]*rsqrtf(v1[e]+1e-5f);
    wbs[g] = f2bf(w1[e*128 + c]*s1);
  } else {
    int g2i = g - 32768;
    int ot = g2i >> 12, kt = (g2i >> 9) & 7, l = (g2i >> 3) & 63, j = g2i & 7;
    int o = ot*16 + (l&15);
    int e = kt*32 + 8*(l>>4) + j;
    float s2 = g2[o]*rsqrtf(v2[o]+1e-5f);
    wbs[32768 + g2i] = f2bf(w2[o*256 + e]*s2);
  }
  if(g < 256){
    float s1 = g1[g]*rsqrtf(v1[g]+1e-5f);
    wb[32768 + g] = b1[g]*s1 + be1[g] - m1[g]*s1;
  }
  if(g < 128){
    float s2 = g2[g]*rsqrtf(v2[g]+1e-5f);
    wb[33024 + g] = b2[g]*s2 + be2[g] - m2[g]*s2;
  }
}

// ---------------- kernel 1: forward 2D DFT via MFMA + fftshift + HPF ---------
// Step A: P[wd][h] = sum_w x[h][w] * F[wd^64][w]   (each wave reads its strip once)
// Step B: D[hd][wd] via swapped MFMA; per-wave scratch transpose makes every
//         4-lane group store 64B contiguous; register-buffered row burst.
__global__ __launch_bounds__(512,4) void k_fft_fwd(const float* __restrict__ x2,
                                                   uint* __restrict__ spec){
  __shared__ ushort Pre[128*TP], Pim[128*TP];   // P stored [wd][h]
  __shared__ ushort scr[8*640];                 // per-wave 1280B scratch
  int t = threadIdx.x, l = t & 63, wv = t >> 6, c = l & 15, q = l >> 4;
  int bid = blockIdx.x, b = bid >> 7, ch = bid & 127;
  const float* src = x2 + (size_t)(b*128 + ch)*PLANE;
  short8 st_r[4][2], st_i[4][2];
  gen_quarter<-1>(st_r, st_i, c, q);
  uint LM = (c&1) ? 0x80008000u : 0u;
  // ---- step A ----
  short8 xa[4];
  #pragma unroll
  for(int kt=0; kt<4; kt++){
    const float* ap = src + (16*wv + c)*128 + kt*32 + 8*q;
    xa[kt] = cvt8(*(const f32x4*)ap, *(const f32x4*)(ap+4));
  }
  #pragma unroll
  for(int ct=0; ct<8; ct++){
    const uint hiM = (ct<4) ? 0x80000000u : 0u;   // rows 16(ct^4)+c
    f32x4 pr = {0,0,0,0}, pi = {0,0,0,0};
    #pragma unroll
    for(int kt=0; kt<4; kt++){
      uint m = ((kt>=2)?LM:0u) ^ hiM;
      pr = __builtin_amdgcn_mfma_f32_16x16x32_bf16(xa[kt], frg(st_r[ct&3][kt&1],m), pr, 0,0,0);
      pi = __builtin_amdgcn_mfma_f32_16x16x32_bf16(xa[kt], frg(st_i[ct&3][kt&1],m), pi, 0,0,0);
    }
    bf16x4 p4r, p4i;
    #pragma unroll
    for(int r=0;r<4;r++){ p4r[r]=f2bf(pr[r]); p4i[r]=f2bf(pi[r]); }
    *(bf16x4*)(&Pre[(16*ct + c)*TP + 16*wv + 4*q]) = p4r;   // P[wd][h]
    *(bf16x4*)(&Pim[(16*ct + c)*TP + 16*wv + 4*q]) = p4i;
  }
  __syncthreads();
  // ---- step B (swapped operands; lane holds hd=16ct+4q+r, wd=16wv+c) ----
  short8 pr_[4], pi_[4];               // B operands: P[wd=16wv+c][h slice]
  #pragma unroll
  for(int kt=0; kt<4; kt++){
    pr_[kt] = *(const short8*)(&Pre[(16*wv + c)*TP + kt*32 + 8*q]);
    pi_[kt] = *(const short8*)(&Pim[(16*wv + c)*TP + kt*32 + 8*q]);
  }
  int bp = (b + 8) & 15, cp = (ch + 64) & 127;
  uint* dst = spec + (size_t)(bp*128 + cp)*PLANE;
  const float SC = 1.0f/128.0f;
  float dw = (float)(16*wv + c) - 63.5f;
  float dw2 = dw*dw;
  uint* tw = ((uint*)scr) + wv*320;    // 16 rows x pitch 20 (dwords)
  u32x4 sbuf[8];
  #pragma unroll
  for(int ct=0; ct<8; ct++){
    const uint hiM = (ct<4) ? 0x80000000u : 0u;   // A rows 16(ct^4)+c
    f32x4 sp = {0,0,0,0}, sn = {0,0,0,0}, si = {0,0,0,0};
    #pragma unroll
    for(int kt=0; kt<4; kt++){
      uint m = ((kt>=2)?LM:0u) ^ hiM;
      short8 br = frg(st_r[ct&3][kt&1], m);
      short8 bi = frg(st_i[ct&3][kt&1], m);
      sp = __builtin_amdgcn_mfma_f32_16x16x32_bf16(br, pr_[kt], sp, 0,0,0);
      sn = __builtin_amdgcn_mfma_f32_16x16x32_bf16(bi, pi_[kt], sn, 0,0,0);
      si = __builtin_amdgcn_mfma_f32_16x16x32_bf16(bi, pr_[kt], si, 0,0,0);
      si = __builtin_amdgcn_mfma_f32_16x16x32_bf16(br, pi_[kt], si, 0,0,0);
    }
    u32x4 outv;
    #pragma unroll
    for(int r=0; r<4; r++){
      float dh = (float)(16*ct + 4*q + r) - 63.5f;
      float mm = (dw2 + dh*dh >= 64.0f) ? SC : 0.0f;
      outv[r] = pk((sp[r]-sn[r])*mm, si[r]*mm);
    }
    // wave-local transpose: (row=wd-off c, cols hd-off 4q..4q+3) -> good map
    *(u32x4*)(tw + c*20 + 4*q) = outv;
    sbuf[ct] = *(const u32x4*)(tw + (l>>2)*20 + (l&3)*4);
  }
  uint* dstw = dst + (16*wv + (l>>2))*128 + (l&3)*4;
  #pragma unroll
  for(int ct=0; ct<8; ct++)            // 4-lane groups write 64B contiguous
    *(u32x4*)(dstw + 16*ct) = sbuf[ct];
}

// ---------------- kernel 2: fused 1x1conv chain via bf16 MFMA ----------------
#define XPITCH 136
#define EPITCH 264
__global__ __launch_bounds__(256,3) void k_conv(const float* __restrict__ wb,
                                                const uint* __restrict__ spec,
                                                uint* __restrict__ zo){
  __shared__ ushort xs[64*XPITCH];
  __shared__ ushort hs[64*EPITCH];
  const ushort* wbs = (const ushort*)wb;
  int bid = blockIdx.x;
  int b = bid >> 9;
  int pix0 = (bid & 511) * 32;
  const uint* sp = spec + (size_t)(b*128)*PLANE + pix0;
  int t = threadIdx.x, l = t & 63, w = t >> 6;
  {
    int p = t & 31, g = t >> 5;
    #pragma unroll
    for(int half=0; half<2; half++){
      ushort re8[8], im8[8];
      #pragma unroll
      for(int k=0;k<8;k++){
        uint u = sp[(size_t)(g*16 + half*8 + k)*PLANE + p];
        re8[k] = (ushort)u; im8[k] = (ushort)(u>>16);
      }
      *(ushort8*)(xs + p*XPITCH      + g*16 + half*8) = *(ushort8*)re8;
      *(ushort8*)(xs + (p+32)*XPITCH + g*16 + half*8) = *(ushort8*)im8;
    }
  }
  short8 bw1[4][4];
  #pragma unroll
  for(int et=0; et<4; et++)
    #pragma unroll
    for(int kt=0; kt<4; kt++)
      bw1[et][kt] = *(const short8*)(wbs + (((w*4+et)*4 + kt)*64 + l)*8);
  float c1v[4];
  #pragma unroll
  for(int et=0; et<4; et++) c1v[et] = wb[32768 + w*64 + et*16 + (l&15)];
  __syncthreads();
  #pragma unroll
  for(int mt=0; mt<4; mt++){
    short8 xa[4];
    #pragma unroll
    for(int kt=0; kt<4; kt++)
      xa[kt] = *(const short8*)(xs + (mt*16 + (l&15))*XPITCH + kt*32 + 8*(l>>4));
    f32x4 a0 = {0,0,0,0}, a1 = {0,0,0,0}, a2 = {0,0,0,0}, a3 = {0,0,0,0};
    #pragma unroll
    for(int kt=0; kt<4; kt++){
      a0 = __builtin_amdgcn_mfma_f32_16x16x32_bf16(xa[kt], bw1[0][kt], a0, 0,0,0);
      a1 = __builtin_amdgcn_mfma_f32_16x16x32_bf16(xa[kt], bw1[1][kt], a1, 0,0,0);
      a2 = __builtin_amdgcn_mfma_f32_16x16x32_bf16(xa[kt], bw1[2][kt], a2, 0,0,0);
      a3 = __builtin_amdgcn_mfma_f32_16x16x32_bf16(xa[kt], bw1[3][kt], a3, 0,0,0);
    }
    #pragma unroll
    for(int et=0; et<4; et++){
      f32x4 av = et==0?a0 : et==1?a1 : et==2?a2 : a3;
      #pragma unroll
      for(int r=0; r<4; r++){
        float h = fmaxf(av[r] + c1v[et], 0.f);
        hs[(mt*16 + (l>>4)*4 + r)*EPITCH + w*64 + et*16 + (l&15)] = f2bf(h);
      }
    }
  }
  short8 aw2[2][8];
  #pragma unroll
  for(int ot=0; ot<2; ot++)
    #pragma unroll
    for(int kt=0; kt<8; kt++)
      aw2[ot][kt] = *(const short8*)(wbs + 32768 + (((w*2+ot)*8 + kt)*64 + l)*8);
  float c2r[8];
  #pragma unroll
  for(int ot=0; ot<2; ot++)
    #pragma unroll
    for(int r=0; r<4; r++)
      c2r[ot*4+r] = wb[33024 + w*32 + ot*16 + (l>>4)*4 + r];
  __syncthreads();
  f32x4 d[2][4];
  #pragma unroll
  for(int ot=0; ot<2; ot++)
    #pragma unroll
    for(int pt=0; pt<4; pt++) d[ot][pt] = (f32x4){0,0,0,0};
  for(int kt=0; kt<8; kt++){
    short8 hb[4];
    #pragma unroll
    for(int pt=0; pt<4; pt++)
      hb[pt] = *(const short8*)(hs + (pt*16 + (l&15))*EPITCH + kt*32 + 8*(l>>4));
    #pragma unroll
    for(int ot=0; ot<2; ot++)
      #pragma unroll
      for(int pt=0; pt<4; pt++)
        d[ot][pt] = __builtin_amdgcn_mfma_f32_16x16x32_bf16(aw2[ot][kt], hb[pt], d[ot][pt], 0,0,0);
  }
  uint* zb = zo + (size_t)(b*128)*PLANE + pix0;
  #pragma unroll
  for(int ot=0; ot<2; ot++){
    #pragma unroll
    for(int pp=0; pp<2; pp++){
      #pragma unroll
      for(int r=0; r<4; r++){
        int o = w*32 + ot*16 + (l>>4)*4 + r;
        int p = pp*16 + (l&15);
        float re = d[ot][pp][r]   + c2r[ot*4+r] + bf2f(xs[p*XPITCH + o]);
        float im = d[ot][pp+2][r] + c2r[ot*4+r] + bf2f(xs[(p+32)*XPITCH + o]);
        zb[(size_t)o*PLANE + p] = pk(re, im);
      }
    }
  }
}

// ---------------- kernel 3: inverse 2D DFT via MFMA + |.| + outputs ----------
// z[wd][hd] bf16 packed (aliases out+2*NTOT, plane-aligned).
// Step A: T[nh][wd] = sum_hd Z[wd][hd]*G[nh][hd]  (strip read once per wave)
// Step B: swapped MFMA (lane: nw=16ct+4q+r, nh=16wv+c); per-wave scratch
//         transpose -> all loads/stores 64B-contiguous per 4-lane group.
__global__ __launch_bounds__(512,4) void k_ifft_out(const uint* z,
                                                    const float* __restrict__ xin1,
                                                    const float* __restrict__ xin2,
                                                    float* out){
  __shared__ ushort Tre[128*TP], Tim[128*TP];   // T stored [nh][wd]
  __shared__ ushort scr[8*640];                 // per-wave 1280B scratch
  int t = threadIdx.x, l = t & 63, wv = t >> 6, c = l & 15, q = l >> 4;
  int bid = blockIdx.x, b = bid >> 7, o = bid & 127;
  size_t plane = (size_t)(b*128 + o)*PLANE;
  const uint* zp = z + plane;
  short8 st_r[4][2], st_i[4][2];
  gen_quarter<1>(st_r, st_i, c, q);
  uint LM = (c&1) ? 0x80008000u : 0u;
  // ---- step A ----
  short8 zr[4], zi[4];
  #pragma unroll
  for(int kt=0; kt<4; kt++){
    const uint* ap = zp + (16*wv + c)*128 + kt*32 + 8*q;
    unpack2(*(const u32x4*)ap, *(const u32x4*)(ap+4), zr[kt], zi[kt]);
  }
  #pragma unroll
  for(int ct=0; ct<8; ct++){
    const uint hiM = (ct>=4) ? 0x80000000u : 0u;
    f32x4 tp = {0,0,0,0}, tn = {0,0,0,0}, ti = {0,0,0,0};
    #pragma unroll
    for(int kt=0; kt<4; kt++){
      uint m = ((kt>=2)?LM:0u) ^ hiM;
      short8 br = frg(st_r[ct&3][kt&1], m);
      short8 bi = frg(st_i[ct&3][kt&1], m);
      tp = __builtin_amdgcn_mfma_f32_16x16x32_bf16(zr[kt], br, tp, 0,0,0);
      tn = __builtin_amdgcn_mfma_f32_16x16x32_bf16(zi[kt], bi, tn, 0,0,0);
      ti = __builtin_amdgcn_mfma_f32_16x16x32_bf16(zr[kt], bi, ti, 0,0,0);
      ti = __builtin_amdgcn_mfma_f32_16x16x32_bf16(zi[kt], br, ti, 0,0,0);
    }
    bf16x4 t4r, t4i;
    #pragma unroll
    for(int r=0;r<4;r++){ t4r[r]=f2bf(tp[r]-tn[r]); t4i[r]=f2bf(ti[r]); }
    *(bf16x4*)(&Tre[(16*ct + c)*TP + 16*wv + 4*q]) = t4r;   // T[nh][wd]
    *(bf16x4*)(&Tim[(16*ct + c)*TP + 16*wv + 4*q]) = t4i;
  }
  __syncthreads();     // all z reads (aliasing hx) complete before any out write
  // ---- step B ----
  short8 tr_[4], ti_[4];               // B operands: T[nh=16wv+c][wd slice]
  #pragma unroll
  for(int kt=0; kt<4; kt++){
    tr_[kt] = *(const short8*)(&Tre[(16*wv + c)*TP + kt*32 + 8*q]);
    ti_[kt] = *(const short8*)(&Tim[(16*wv + c)*TP + kt*32 + 8*q]);
  }
  const float SC = 1.0f/128.0f;
  float* hw = ((float*)scr) + wv*320;  // 16 rows x pitch 20 (floats)
  f32x4 hbuf[8];
  #pragma unroll
  for(int ct=0; ct<8; ct++){
    const uint hiM = (ct>=4) ? 0x80000000u : 0u;  // A rows nw = 16ct+c
    f32x4 sp = {0,0,0,0}, sn = {0,0,0,0}, si = {0,0,0,0};
    #pragma unroll
    for(int kt=0; kt<4; kt++){
      uint m = ((kt>=2)?LM:0u) ^ hiM;
      short8 br = frg(st_r[ct&3][kt&1], m);
      short8 bi = frg(st_i[ct&3][kt&1], m);
      sp = __builtin_amdgcn_mfma_f32_16x16x32_bf16(br, tr_[kt], sp, 0,0,0);
      sn = __builtin_amdgcn_mfma_f32_16x16x32_bf16(bi, ti_[kt], sn, 0,0,0);
      si = __builtin_amdgcn_mfma_f32_16x16x32_bf16(bi, tr_[kt], si, 0,0,0);
      si = __builtin_amdgcn_mfma_f32_16x16x32_bf16(br, ti_[kt], si, 0,0,0);
    }
    f32x4 h4;
    #pragma unroll
    for(int r=0; r<4; r++){
      float re = sp[r]-sn[r], im = si[r];
      h4[r] = sqrtf(re*re + im*im) * SC;
    }
    // wave-local transpose: (row=nh-off c, cols nw-off 4q..4q+3) -> good map
    *(f32x4*)(hw + c*20 + 4*q) = h4;
    hbuf[ct] = *(const f32x4*)(hw + (l>>2)*20 + (l&3)*4);
  }
  // epilogue: every 4-lane group loads/stores 64B contiguous
  size_t rowb = plane + (size_t)(16*wv + (l>>2))*128 + (l&3)*4;
  #pragma unroll
  for(int ct=0; ct<8; ct++){
    size_t i0 = rowb + 16*ct;
    f32x4 u = *(const f32x4*)(xin1 + i0);
    f32x4 v = *(const f32x4*)(xin2 + i0);
    f32x4 h4 = hbuf[ct], o1, o2;
    #pragma unroll
    for(int j=0;j<4;j++){ o1[j] = u[j]*h4[j] + u[j]; o2[j] = v[j]*h4[j] + v[j]; }
    *(f32x4*)(out + i0) = o1;
    *(f32x4*)(out + NTOT + i0) = o2;
    *(f32x4*)(out + 2u*NTOT + i0) = h4;
  }
}

extern "C" void kernel_launch(void* const* d_in, const int* in_sizes, int n_in,
                              void* d_out, int out_size, void* d_ws, size_t ws_size,
                              hipStream_t stream){
  (void)in_sizes; (void)n_in; (void)d_ws; (void)ws_size; (void)out_size;
  const float* x1  = (const float*)d_in[0];
  const float* x2  = (const float*)d_in[1];
  const float* w1  = (const float*)d_in[2];
  const float* b1  = (const float*)d_in[3];
  const float* g1  = (const float*)d_in[4];
  const float* be1 = (const float*)d_in[5];
  const float* m1  = (const float*)d_in[6];
  const float* v1  = (const float*)d_in[7];
  const float* w2  = (const float*)d_in[8];
  const float* b2  = (const float*)d_in[9];
  const float* g2  = (const float*)d_in[10];
  const float* be2 = (const float*)d_in[11];
  const float* m2  = (const float*)d_in[12];
  const float* v2  = (const float*)d_in[13];
  float* out = (float*)d_out;
  float* wb   = out;                       // slot0: weights (dead after conv)
  uint*  spec = (uint*)(out + NTOT);       // slot1: bf16 spectrum (dead after conv)
  uint*  z    = (uint*)(out + 2u*NTOT);    // slot2: bf16 z, plane-aliased with hx
  hipLaunchKernelGGL(k_prep,     dim3(256),  dim3(256), 0, stream,
                     w1,b1,g1,be1,m1,v1,w2,b2,g2,be2,m2,v2, wb);
  hipLaunchKernelGGL(k_fft_fwd,  dim3(2048), dim3(512), 0, stream, x2, spec);
  hipLaunchKernelGGL(k_conv,     dim3(8192), dim3(256), 0, stream, wb, spec, z);
  hipLaunchKernelGGL(k_ifft_out, dim3(2048), dim3(512), 0, stream, z, x1, x2, out);
}

// Round 12
// 957.421 us; speedup vs baseline: 1.1854x; 1.1854x over previous
//
#include <hip/hip_runtime.h>
#include <math.h>

#define PLANE 16384
#define NTOT  33554432u
#define TP    136            // LDS row pitch in shorts for T/P arrays
#define HP    132            // pitch (dwords/floats) for the step-B result plane
typedef unsigned int  uint;
typedef unsigned short ushort;

typedef __attribute__((ext_vector_type(8))) short  short8;
typedef __attribute__((ext_vector_type(8))) ushort ushort8;
typedef __attribute__((ext_vector_type(4))) ushort bf16x4;
typedef __attribute__((ext_vector_type(4))) uint   u32x4;
typedef __attribute__((ext_vector_type(4))) float  f32x4;

__device__ __forceinline__ ushort f2bf(float x){
  unsigned u = __float_as_uint(x);
  u = (u + 0x7FFFu + ((u >> 16) & 1u)) >> 16;
  return (ushort)u;
}
__device__ __forceinline__ float bf2f(ushort h){
  return __uint_as_float(((uint)h) << 16);
}
__device__ __forceinline__ uint pk(float a, float b){
  return (uint)f2bf(a) | ((uint)f2bf(b) << 16);
}
// split packed (re,im) bf16 dwords into two short8 fragments
__device__ __forceinline__ void unpack2(u32x4 a, u32x4 b, short8& re, short8& im){
  union { uint u[4]; short8 s; } R, I;
  R.u[0] = (a[0]&0xffffu) | (a[1]<<16);
  R.u[1] = (a[2]&0xffffu) | (a[3]<<16);
  R.u[2] = (b[0]&0xffffu) | (b[1]<<16);
  R.u[3] = (b[2]&0xffffu) | (b[3]<<16);
  I.u[0] = (a[0]>>16) | (a[1]&0xffff0000u);
  I.u[1] = (a[2]>>16) | (a[3]&0xffff0000u);
  I.u[2] = (b[0]>>16) | (b[1]&0xffff0000u);
  I.u[3] = (b[2]>>16) | (b[3]&0xffff0000u);
  re = R.s; im = I.s;
}
__device__ __forceinline__ short8 cvt8(f32x4 a, f32x4 b){
  union { ushort h[8]; short8 s; } r;
  #pragma unroll
  for(int j=0;j<4;j++){ r.h[j]=f2bf(a[j]); r.h[4+j]=f2bf(b[j]); }
  return r.s;
}
// apply sign mask (bf16 sign-bit flips) to a fragment
__device__ __forceinline__ short8 frg(short8 base, uint m){
  union { short8 s; u32x4 u; } x; x.s = base;
  x.u[0]^=m; x.u[1]^=m; x.u[2]^=m; x.u[3]^=m;
  return x.s;
}
#define W128 0.049087385212340517f   // 2*pi/128

// quarter twiddle table in registers: rows n=16a+c (a<4 -> n<64),
// k = kk*32 + 8q + j (kk<2 -> k<64). Extend via:
//   n>=64: *(-1)^k  -> XOR 0x80000000 (odd-j shorts)   [hiM]
//   k>=64: *(-1)^n  -> XOR 0x80008000 if c odd          [LM]
template<int SGN>
__device__ __forceinline__ void gen_quarter(short8 (&st_r)[4][2], short8 (&st_i)[4][2],
                                            int c, int q){
  #pragma unroll
  for(int a=0;a<4;a++){
    int n = 16*a + c;
    #pragma unroll
    for(int kk=0;kk<2;kk++){
      union{ushort h[8]; short8 s;} R, I;
      #pragma unroll
      for(int j=0;j<8;j++){
        int k = kk*32 + 8*q + j;
        float ss, cc; __sincosf((float)((n*k)&127)*W128, &ss, &cc);
        R.h[j] = f2bf(cc); I.h[j] = f2bf(SGN < 0 ? -ss : ss);
      }
      st_r[a][kk]=R.s; st_i[a][kk]=I.s;
    }
  }
}

// ---------------- kernel 0: fold BN, emit MFMA-fragment-packed bf16 weights --
__global__ __launch_bounds__(256) void k_prep(
    const float* __restrict__ w1, const float* __restrict__ b1,
    const float* __restrict__ g1, const float* __restrict__ be1,
    const float* __restrict__ m1, const float* __restrict__ v1,
    const float* __restrict__ w2, const float* __restrict__ b2,
    const float* __restrict__ g2, const float* __restrict__ be2,
    const float* __restrict__ m2, const float* __restrict__ v2,
    float* __restrict__ wb){
  int g = blockIdx.x*256 + threadIdx.x;      // 65536 threads
  ushort* wbs = (ushort*)wb;
  if(g < 32768){
    int kt = (g >> 9) & 3, l = (g >> 3) & 63, j = g & 7;
    int et = g >> 11;
    int c = kt*32 + 8*(l>>4) + j;
    int e = et*16 + (l&15);
    float s1 = g1[e]*rsqrtf(v1[e]+1e-5f);
    wbs[g] = f2bf(w1[e*128 + c]*s1);
  } else {
    int g2i = g - 32768;
    int ot = g2i >> 12, kt = (g2i >> 9) & 7, l = (g2i >> 3) & 63, j = g2i & 7;
    int o = ot*16 + (l&15);
    int e = kt*32 + 8*(l>>4) + j;
    float s2 = g2[o]*rsqrtf(v2[o]+1e-5f);
    wbs[32768 + g2i] = f2bf(w2[o*256 + e]*s2);
  }
  if(g < 256){
    float s1 = g1[g]*rsqrtf(v1[g]+1e-5f);
    wb[32768 + g] = b1[g]*s1 + be1[g] - m1[g]*s1;
  }
  if(g < 128){
    float s2 = g2[g]*rsqrtf(v2[g]+1e-5f);
    wb[33024 + g] = b2[g]*s2 + be2[g] - m2[g]*s2;
  }
}

// ---------------- kernel 1: forward 2D DFT via MFMA + fftshift + HPF ---------
// Step A: P[wd][h] = sum_w x[h][w] * F[wd^64][w]   (each wave reads its strip once)
// Step B: swapped MFMA -> results into LDS uint plane [wd][hd], then a flat
//         copy-out: every store instruction covers 1KB contiguous (8 full lines).
__global__ __launch_bounds__(512,4) void k_fft_fwd(const float* __restrict__ x2,
                                                   uint* __restrict__ spec){
  __shared__ ushort PP[2*128*TP];               // Pre|Pim, reused as sb[128][HP]
  ushort* Pre = PP;
  ushort* Pim = PP + 128*TP;
  int t = threadIdx.x, l = t & 63, wv = t >> 6, c = l & 15, q = l >> 4;
  int bid = blockIdx.x, b = bid >> 7, ch = bid & 127;
  const float* src = x2 + (size_t)(b*128 + ch)*PLANE;
  short8 st_r[4][2], st_i[4][2];
  gen_quarter<-1>(st_r, st_i, c, q);
  uint LM = (c&1) ? 0x80008000u : 0u;
  // ---- step A ----
  short8 xa[4];
  #pragma unroll
  for(int kt=0; kt<4; kt++){
    const float* ap = src + (16*wv + c)*128 + kt*32 + 8*q;
    xa[kt] = cvt8(*(const f32x4*)ap, *(const f32x4*)(ap+4));
  }
  #pragma unroll
  for(int ct=0; ct<8; ct++){
    const uint hiM = (ct<4) ? 0x80000000u : 0u;   // rows 16(ct^4)+c
    f32x4 pr = {0,0,0,0}, pi = {0,0,0,0};
    #pragma unroll
    for(int kt=0; kt<4; kt++){
      uint m = ((kt>=2)?LM:0u) ^ hiM;
      pr = __builtin_amdgcn_mfma_f32_16x16x32_bf16(xa[kt], frg(st_r[ct&3][kt&1],m), pr, 0,0,0);
      pi = __builtin_amdgcn_mfma_f32_16x16x32_bf16(xa[kt], frg(st_i[ct&3][kt&1],m), pi, 0,0,0);
    }
    bf16x4 p4r, p4i;
    #pragma unroll
    for(int r=0;r<4;r++){ p4r[r]=f2bf(pr[r]); p4i[r]=f2bf(pi[r]); }
    *(bf16x4*)(&Pre[(16*ct + c)*TP + 16*wv + 4*q]) = p4r;   // P[wd][h]
    *(bf16x4*)(&Pim[(16*ct + c)*TP + 16*wv + 4*q]) = p4i;
  }
  __syncthreads();
  // ---- step B (swapped operands; lane holds hd=16ct+4q+r, wd=16wv+c) ----
  short8 pr_[4], pi_[4];               // B operands: P[wd=16wv+c][h slice]
  #pragma unroll
  for(int kt=0; kt<4; kt++){
    pr_[kt] = *(const short8*)(&Pre[(16*wv + c)*TP + kt*32 + 8*q]);
    pi_[kt] = *(const short8*)(&Pim[(16*wv + c)*TP + kt*32 + 8*q]);
  }
  __syncthreads();                     // P consumed; PP reusable as sb
  uint* sb = (uint*)PP;                // sb[wd][hd], pitch HP
  const float SC = 1.0f/128.0f;
  float dw = (float)(16*wv + c) - 63.5f;
  float dw2 = dw*dw;
  #pragma unroll
  for(int ct=0; ct<8; ct++){
    const uint hiM = (ct<4) ? 0x80000000u : 0u;   // A rows 16(ct^4)+c
    f32x4 sp = {0,0,0,0}, sn = {0,0,0,0}, si = {0,0,0,0};
    #pragma unroll
    for(int kt=0; kt<4; kt++){
      uint m = ((kt>=2)?LM:0u) ^ hiM;
      short8 br = frg(st_r[ct&3][kt&1], m);
      short8 bi = frg(st_i[ct&3][kt&1], m);
      sp = __builtin_amdgcn_mfma_f32_16x16x32_bf16(br, pr_[kt], sp, 0,0,0);
      sn = __builtin_amdgcn_mfma_f32_16x16x32_bf16(bi, pi_[kt], sn, 0,0,0);
      si = __builtin_amdgcn_mfma_f32_16x16x32_bf16(bi, pr_[kt], si, 0,0,0);
      si = __builtin_amdgcn_mfma_f32_16x16x32_bf16(br, pi_[kt], si, 0,0,0);
    }
    u32x4 outv;
    #pragma unroll
    for(int r=0; r<4; r++){
      float dh = (float)(16*ct + 4*q + r) - 63.5f;
      float mm = (dw2 + dh*dh >= 64.0f) ? SC : 0.0f;
      outv[r] = pk((sp[r]-sn[r])*mm, si[r]*mm);
    }
    *(u32x4*)(&sb[(16*wv + c)*HP + 16*ct + 4*q]) = outv;
  }
  __syncthreads();
  // ---- flat copy-out: 1KB contiguous per store instruction ----
  int bp = (b + 8) & 15, cp = (ch + 64) & 127;
  uint* dst = spec + (size_t)(bp*128 + cp)*PLANE;
  #pragma unroll
  for(int i=0; i<8; i++){
    int p = i*2048 + 4*t;
    u32x4 v = *(const u32x4*)(&sb[(p>>7)*HP + (p&127)]);
    *(u32x4*)(dst + p) = v;
  }
}

// ---------------- kernel 2: fused 1x1conv chain via bf16 MFMA ----------------
#define XPITCH 136
#define EPITCH 264
__global__ __launch_bounds__(256,3) void k_conv(const float* __restrict__ wb,
                                                const uint* __restrict__ spec,
                                                uint* __restrict__ zo){
  __shared__ ushort xs[64*XPITCH];
  __shared__ ushort hs[64*EPITCH];
  const ushort* wbs = (const ushort*)wb;
  int bid = blockIdx.x;
  int b = bid >> 9;
  int pix0 = (bid & 511) * 32;
  const uint* sp = spec + (size_t)(b*128)*PLANE + pix0;
  int t = threadIdx.x, l = t & 63, w = t >> 6;
  {
    int p = t & 31, g = t >> 5;
    #pragma unroll
    for(int half=0; half<2; half++){
      ushort re8[8], im8[8];
      #pragma unroll
      for(int k=0;k<8;k++){
        uint u = sp[(size_t)(g*16 + half*8 + k)*PLANE + p];
        re8[k] = (ushort)u; im8[k] = (ushort)(u>>16);
      }
      *(ushort8*)(xs + p*XPITCH      + g*16 + half*8) = *(ushort8*)re8;
      *(ushort8*)(xs + (p+32)*XPITCH + g*16 + half*8) = *(ushort8*)im8;
    }
  }
  short8 bw1[4][4];
  #pragma unroll
  for(int et=0; et<4; et++)
    #pragma unroll
    for(int kt=0; kt<4; kt++)
      bw1[et][kt] = *(const short8*)(wbs + (((w*4+et)*4 + kt)*64 + l)*8);
  float c1v[4];
  #pragma unroll
  for(int et=0; et<4; et++) c1v[et] = wb[32768 + w*64 + et*16 + (l&15)];
  __syncthreads();
  #pragma unroll
  for(int mt=0; mt<4; mt++){
    short8 xa[4];
    #pragma unroll
    for(int kt=0; kt<4; kt++)
      xa[kt] = *(const short8*)(xs + (mt*16 + (l&15))*XPITCH + kt*32 + 8*(l>>4));
    f32x4 a0 = {0,0,0,0}, a1 = {0,0,0,0}, a2 = {0,0,0,0}, a3 = {0,0,0,0};
    #pragma unroll
    for(int kt=0; kt<4; kt++){
      a0 = __builtin_amdgcn_mfma_f32_16x16x32_bf16(xa[kt], bw1[0][kt], a0, 0,0,0);
      a1 = __builtin_amdgcn_mfma_f32_16x16x32_bf16(xa[kt], bw1[1][kt], a1, 0,0,0);
      a2 = __builtin_amdgcn_mfma_f32_16x16x32_bf16(xa[kt], bw1[2][kt], a2, 0,0,0);
      a3 = __builtin_amdgcn_mfma_f32_16x16x32_bf16(xa[kt], bw1[3][kt], a3, 0,0,0);
    }
    #pragma unroll
    for(int et=0; et<4; et++){
      f32x4 av = et==0?a0 : et==1?a1 : et==2?a2 : a3;
      #pragma unroll
      for(int r=0; r<4; r++){
        float h = fmaxf(av[r] + c1v[et], 0.f);
        hs[(mt*16 + (l>>4)*4 + r)*EPITCH + w*64 + et*16 + (l&15)] = f2bf(h);
      }
    }
  }
  short8 aw2[2][8];
  #pragma unroll
  for(int ot=0; ot<2; ot++)
    #pragma unroll
    for(int kt=0; kt<8; kt++)
      aw2[ot][kt] = *(const short8*)(wbs + 32768 + (((w*2+ot)*8 + kt)*64 + l)*8);
  float c2r[8];
  #pragma unroll
  for(int ot=0; ot<2; ot++)
    #pragma unroll
    for(int r=0; r<4; r++)
      c2r[ot*4+r] = wb[33024 + w*32 + ot*16 + (l>>4)*4 + r];
  __syncthreads();
  f32x4 d[2][4];
  #pragma unroll
  for(int ot=0; ot<2; ot++)
    #pragma unroll
    for(int pt=0; pt<4; pt++) d[ot][pt] = (f32x4){0,0,0,0};
  for(int kt=0; kt<8; kt++){
    short8 hb[4];
    #pragma unroll
    for(int pt=0; pt<4; pt++)
      hb[pt] = *(const short8*)(hs + (pt*16 + (l&15))*EPITCH + kt*32 + 8*(l>>4));
    #pragma unroll
    for(int ot=0; ot<2; ot++)
      #pragma unroll
      for(int pt=0; pt<4; pt++)
        d[ot][pt] = __builtin_amdgcn_mfma_f32_16x16x32_bf16(aw2[ot][kt], hb[pt], d[ot][pt], 0,0,0);
  }
  uint* zb = zo + (size_t)(b*128)*PLANE + pix0;
  #pragma unroll
  for(int ot=0; ot<2; ot++){
    #pragma unroll
    for(int pp=0; pp<2; pp++){
      #pragma unroll
      for(int r=0; r<4; r++){
        int o = w*32 + ot*16 + (l>>4)*4 + r;
        int p = pp*16 + (l&15);
        float re = d[ot][pp][r]   + c2r[ot*4+r] + bf2f(xs[p*XPITCH + o]);
        float im = d[ot][pp+2][r] + c2r[ot*4+r] + bf2f(xs[(p+32)*XPITCH + o]);
        zb[(size_t)o*PLANE + p] = pk(re, im);
      }
    }
  }
}

// ---------------- kernel 3: inverse 2D DFT via MFMA + |.| + outputs ----------
// z[wd][hd] bf16 packed (aliases out+2*NTOT, plane-aligned).
// Step A: T[nh][wd] = sum_hd Z[wd][hd]*G[nh][hd]  (strip read once per wave)
// Step B: swapped MFMA -> h into LDS f32 plane [nh][nw]; flat epilogue:
//         every load/store instruction covers 1KB contiguous (8 full lines).
__global__ __launch_bounds__(512,4) void k_ifft_out(const uint* z,
                                                    const float* __restrict__ xin1,
                                                    const float* __restrict__ xin2,
                                                    float* out){
  __shared__ ushort TT[2*128*TP];               // Tre|Tim, reused as hb[128][HP] f32
  ushort* Tre = TT;
  ushort* Tim = TT + 128*TP;
  int t = threadIdx.x, l = t & 63, wv = t >> 6, c = l & 15, q = l >> 4;
  int bid = blockIdx.x, b = bid >> 7, o = bid & 127;
  size_t plane = (size_t)(b*128 + o)*PLANE;
  const uint* zp = z + plane;
  short8 st_r[4][2], st_i[4][2];
  gen_quarter<1>(st_r, st_i, c, q);
  uint LM = (c&1) ? 0x80008000u : 0u;
  // ---- step A ----
  short8 zr[4], zi[4];
  #pragma unroll
  for(int kt=0; kt<4; kt++){
    const uint* ap = zp + (16*wv + c)*128 + kt*32 + 8*q;
    unpack2(*(const u32x4*)ap, *(const u32x4*)(ap+4), zr[kt], zi[kt]);
  }
  #pragma unroll
  for(int ct=0; ct<8; ct++){
    const uint hiM = (ct>=4) ? 0x80000000u : 0u;
    f32x4 tp = {0,0,0,0}, tn = {0,0,0,0}, ti = {0,0,0,0};
    #pragma unroll
    for(int kt=0; kt<4; kt++){
      uint m = ((kt>=2)?LM:0u) ^ hiM;
      short8 br = frg(st_r[ct&3][kt&1], m);
      short8 bi = frg(st_i[ct&3][kt&1], m);
      tp = __builtin_amdgcn_mfma_f32_16x16x32_bf16(zr[kt], br, tp, 0,0,0);
      tn = __builtin_amdgcn_mfma_f32_16x16x32_bf16(zi[kt], bi, tn, 0,0,0);
      ti = __builtin_amdgcn_mfma_f32_16x16x32_bf16(zr[kt], bi, ti, 0,0,0);
      ti = __builtin_amdgcn_mfma_f32_16x16x32_bf16(zi[kt], br, ti, 0,0,0);
    }
    bf16x4 t4r, t4i;
    #pragma unroll
    for(int r=0;r<4;r++){ t4r[r]=f2bf(tp[r]-tn[r]); t4i[r]=f2bf(ti[r]); }
    *(bf16x4*)(&Tre[(16*ct + c)*TP + 16*wv + 4*q]) = t4r;   // T[nh][wd]
    *(bf16x4*)(&Tim[(16*ct + c)*TP + 16*wv + 4*q]) = t4i;
  }
  __syncthreads();     // all z reads (aliasing hx) complete before any out write
  // ---- step B ----
  short8 tr_[4], ti_[4];               // B operands: T[nh=16wv+c][wd slice]
  #pragma unroll
  for(int kt=0; kt<4; kt++){
    tr_[kt] = *(const short8*)(&Tre[(16*wv + c)*TP + kt*32 + 8*q]);
    ti_[kt] = *(const short8*)(&Tim[(16*wv + c)*TP + kt*32 + 8*q]);
  }
  __syncthreads();                     // T consumed; TT reusable as hb
  float* hb = (float*)TT;              // hb[nh][nw], pitch HP, f32 (exact)
  const float SC = 1.0f/128.0f;
  #pragma unroll
  for(int ct=0; ct<8; ct++){
    const uint hiM = (ct>=4) ? 0x80000000u : 0u;  // A rows nw = 16ct+c
    f32x4 sp = {0,0,0,0}, sn = {0,0,0,0}, si = {0,0,0,0};
    #pragma unroll
    for(int kt=0; kt<4; kt++){
      uint m = ((kt>=2)?LM:0u) ^ hiM;
      short8 br = frg(st_r[ct&3][kt&1], m);
      short8 bi = frg(st_i[ct&3][kt&1], m);
      sp = __builtin_amdgcn_mfma_f32_16x16x32_bf16(br, tr_[kt], sp, 0,0,0);
      sn = __builtin_amdgcn_mfma_f32_16x16x32_bf16(bi, ti_[kt], sn, 0,0,0);
      si = __builtin_amdgcn_mfma_f32_16x16x32_bf16(bi, tr_[kt], si, 0,0,0);
      si = __builtin_amdgcn_mfma_f32_16x16x32_bf16(br, ti_[kt], si, 0,0,0);
    }
    f32x4 h4;
    #pragma unroll
    for(int r=0; r<4; r++){
      float re = sp[r]-sn[r], im = si[r];
      h4[r] = sqrtf(re*re + im*im) * SC;
    }
    *(f32x4*)(&hb[(16*wv + c)*HP + 16*ct + 4*q]) = h4;   // h[nh][nw]
  }
  __syncthreads();
  // ---- flat epilogue: 1KB contiguous per load/store instruction ----
  #pragma unroll
  for(int i=0; i<8; i++){
    int p = i*2048 + 4*t;
    f32x4 h4 = *(const f32x4*)(&hb[(p>>7)*HP + (p&127)]);
    size_t idx = plane + p;
    f32x4 u = *(const f32x4*)(xin1 + idx);
    f32x4 v = *(const f32x4*)(xin2 + idx);
    f32x4 o1, o2;
    #pragma unroll
    for(int j=0;j<4;j++){ o1[j] = u[j]*h4[j] + u[j]; o2[j] = v[j]*h4[j] + v[j]; }
    *(f32x4*)(out + idx) = o1;
    *(f32x4*)(out + NTOT + idx) = o2;
    *(f32x4*)(out + 2u*NTOT + idx) = h4;
  }
}

extern "C" void kernel_launch(void* const* d_in, const int* in_sizes, int n_in,
                              void* d_out, int out_size, void* d_ws, size_t ws_size,
                              hipStream_t stream){
  (void)in_sizes; (void)n_in; (void)d_ws; (void)ws_size; (void)out_size;
  const float* x1  = (const float*)d_in[0];
  const float* x2  = (const float*)d_in[1];
  const float* w1  = (const float*)d_in[2];
  const float* b1  = (const float*)d_in[3];
  const float* g1  = (const float*)d_in[4];
  const float* be1 = (const float*)d_in[5];
  const float* m1  = (const float*)d_in[6];
  const float* v1  = (const float*)d_in[7];
  const float* w2  = (const float*)d_in[8];
  const float* b2  = (const float*)d_in[9];
  const float* g2  = (const float*)d_in[10];
  const float* be2 = (const float*)d_in[11];
  const float* m2  = (const float*)d_in[12];
  const float* v2  = (const float*)d_in[13];
  float* out = (float*)d_out;
  float* wb   = out;                       // slot0: weights (dead after conv)
  uint*  spec = (uint*)(out + NTOT);       // slot1: bf16 spectrum (dead after conv)
  uint*  z    = (uint*)(out + 2u*NTOT);    // slot2: bf16 z, plane-aliased with hx
  hipLaunchKernelGGL(k_prep,     dim3(256),  dim3(256), 0, stream,
                     w1,b1,g1,be1,m1,v1,w2,b2,g2,be2,m2,v2, wb);
  hipLaunchKernelGGL(k_fft_fwd,  dim3(2048), dim3(512), 0, stream, x2, spec);
  hipLaunchKernelGGL(k_conv,     dim3(8192), dim3(256), 0, stream, wb, spec, z);
  hipLaunchKernelGGL(k_ifft_out, dim3(2048), dim3(512), 0, stream, z, x1, x2, out);
}

// Round 13
// 512.326 us; speedup vs baseline: 2.2152x; 1.8688x over previous
//
#include <hip/hip_runtime.h>
#include <math.h>

#define PLANE 16384
#define NTOT  33554432u
#define TP    136            // LDS row pitch in shorts for T/P arrays
typedef unsigned int  uint;
typedef unsigned short ushort;

typedef __attribute__((ext_vector_type(8))) short  short8;
typedef __attribute__((ext_vector_type(8))) ushort ushort8;
typedef __attribute__((ext_vector_type(4))) ushort bf16x4;
typedef __attribute__((ext_vector_type(4))) uint   u32x4;
typedef __attribute__((ext_vector_type(4))) float  f32x4;

__device__ __forceinline__ ushort f2bf(float x){
  unsigned u = __float_as_uint(x);
  u = (u + 0x7FFFu + ((u >> 16) & 1u)) >> 16;
  return (ushort)u;
}
__device__ __forceinline__ float bf2f(ushort h){
  return __uint_as_float(((uint)h) << 16);
}
__device__ __forceinline__ uint pk(float a, float b){
  return (uint)f2bf(a) | ((uint)f2bf(b) << 16);
}
// split packed (re,im) bf16 dwords into two short8 fragments
__device__ __forceinline__ void unpack2(u32x4 a, u32x4 b, short8& re, short8& im){
  union { uint u[4]; short8 s; } R, I;
  R.u[0] = (a[0]&0xffffu) | (a[1]<<16);
  R.u[1] = (a[2]&0xffffu) | (a[3]<<16);
  R.u[2] = (b[0]&0xffffu) | (b[1]<<16);
  R.u[3] = (b[2]&0xffffu) | (b[3]<<16);
  I.u[0] = (a[0]>>16) | (a[1]&0xffff0000u);
  I.u[1] = (a[2]>>16) | (a[3]&0xffff0000u);
  I.u[2] = (b[0]>>16) | (b[1]&0xffff0000u);
  I.u[3] = (b[2]>>16) | (b[3]&0xffff0000u);
  re = R.s; im = I.s;
}
__device__ __forceinline__ short8 cvt8(f32x4 a, f32x4 b){
  union { ushort h[8]; short8 s; } r;
  #pragma unroll
  for(int j=0;j<4;j++){ r.h[j]=f2bf(a[j]); r.h[4+j]=f2bf(b[j]); }
  return r.s;
}
// apply sign mask (bf16 sign-bit flips) to a fragment
__device__ __forceinline__ short8 frg(short8 base, uint m){
  union { short8 s; u32x4 u; } x; x.s = base;
  x.u[0]^=m; x.u[1]^=m; x.u[2]^=m; x.u[3]^=m;
  return x.s;
}
#define W128 0.049087385212340517f   // 2*pi/128

// quarter twiddle table in registers: rows n=16a+c (a<4 -> n<64),
// k = kk*32 + 8q + j (kk<2 -> k<64). Extend via:
//   n>=64: *(-1)^k  -> XOR 0x80000000 (odd-j shorts)   [hiM]
//   k>=64: *(-1)^n  -> XOR 0x80008000 if c odd          [LM]
template<int SGN>
__device__ __forceinline__ void gen_quarter(short8 (&st_r)[4][2], short8 (&st_i)[4][2],
                                            int c, int q){
  #pragma unroll
  for(int a=0;a<4;a++){
    int n = 16*a + c;
    #pragma unroll
    for(int kk=0;kk<2;kk++){
      union{ushort h[8]; short8 s;} R, I;
      #pragma unroll
      for(int j=0;j<8;j++){
        int k = kk*32 + 8*q + j;
        float ss, cc; __sincosf((float)((n*k)&127)*W128, &ss, &cc);
        R.h[j] = f2bf(cc); I.h[j] = f2bf(SGN < 0 ? -ss : ss);
      }
      st_r[a][kk]=R.s; st_i[a][kk]=I.s;
    }
  }
}

// ---------------- kernel 0: fold BN, emit MFMA-fragment-packed bf16 weights --
__global__ __launch_bounds__(256) void k_prep(
    const float* __restrict__ w1, const float* __restrict__ b1,
    const float* __restrict__ g1, const float* __restrict__ be1,
    const float* __restrict__ m1, const float* __restrict__ v1,
    const float* __restrict__ w2, const float* __restrict__ b2,
    const float* __restrict__ g2, const float* __restrict__ be2,
    const float* __restrict__ m2, const float* __restrict__ v2,
    float* __restrict__ wb){
  int g = blockIdx.x*256 + threadIdx.x;      // 65536 threads
  ushort* wbs = (ushort*)wb;
  if(g < 32768){
    int kt = (g >> 9) & 3, l = (g >> 3) & 63, j = g & 7;
    int et = g >> 11;
    int c = kt*32 + 8*(l>>4) + j;
    int e = et*16 + (l&15);
    float s1 = g1[e]*rsqrtf(v1[e]+1e-5f);
    wbs[g] = f2bf(w1[e*128 + c]*s1);
  } else {
    int g2i = g - 32768;
    int ot = g2i >> 12, kt = (g2i >> 9) & 7, l = (g2i >> 3) & 63, j = g2i & 7;
    int o = ot*16 + (l&15);
    int e = kt*32 + 8*(l>>4) + j;
    float s2 = g2[o]*rsqrtf(v2[o]+1e-5f);
    wbs[32768 + g2i] = f2bf(w2[o*256 + e]*s2);
  }
  if(g < 256){
    float s1 = g1[g]*rsqrtf(v1[g]+1e-5f);
    wb[32768 + g] = b1[g]*s1 + be1[g] - m1[g]*s1;
  }
  if(g < 128){
    float s2 = g2[g]*rsqrtf(v2[g]+1e-5f);
    wb[33024 + g] = b2[g]*s2 + be2[g] - m2[g]*s2;
  }
}

// ---------------- kernel 1: forward 2D DFT via MFMA + fftshift + HPF ---------
// 1 blk/CU (LDS-padded) — empirically required for clean write traffic.
// Step A: P[wd][h] = sum_w x[h][w] * F[wd^64][w]   (rows 16wv+c read once)
// Step B: S[wd][hd] = sum_h P[wd][h] * F[hd^64][h]; per-ct interleaved
//         transposed epilogue (R6-proven clean store pattern).
__global__ __launch_bounds__(512,1) void k_fft_fwd(const float* __restrict__ x2,
                                                   uint* __restrict__ spec){
  __shared__ ushort Pre[128*TP], Pim[128*TP];   // P stored [wd][h]  (69.6 KB)
  __shared__ ushort scr[8*640 + 10240];         // wave scratch + pad -> 1 blk/CU
  int t = threadIdx.x, l = t & 63, wv = t >> 6, c = l & 15, q = l >> 4;
  int bid = blockIdx.x, b = bid >> 7, ch = bid & 127;
  const float* src = x2 + (size_t)(b*128 + ch)*PLANE;
  short8 st_r[4][2], st_i[4][2];
  gen_quarter<-1>(st_r, st_i, c, q);
  uint LM = (c&1) ? 0x80008000u : 0u;
  // ---- step A: A rows h=16wv+c (read once), B rows wd'=16(ct^4)+c ----
  short8 xa[4];
  #pragma unroll
  for(int kt=0; kt<4; kt++){
    const float* ap = src + (16*wv + c)*128 + kt*32 + 8*q;
    xa[kt] = cvt8(*(const f32x4*)ap, *(const f32x4*)(ap+4));
  }
  #pragma unroll
  for(int ct=0; ct<8; ct++){
    const uint hiM = (ct<4) ? 0x80000000u : 0u;
    f32x4 pr = {0,0,0,0}, pi = {0,0,0,0};
    #pragma unroll
    for(int kt=0; kt<4; kt++){
      uint m = ((kt>=2)?LM:0u) ^ hiM;
      pr = __builtin_amdgcn_mfma_f32_16x16x32_bf16(xa[kt], frg(st_r[ct&3][kt&1],m), pr, 0,0,0);
      pi = __builtin_amdgcn_mfma_f32_16x16x32_bf16(xa[kt], frg(st_i[ct&3][kt&1],m), pi, 0,0,0);
    }
    bf16x4 p4r, p4i;
    #pragma unroll
    for(int r=0;r<4;r++){ p4r[r]=f2bf(pr[r]); p4i[r]=f2bf(pi[r]); }
    *(bf16x4*)(&Pre[(16*ct + c)*TP + 16*wv + 4*q]) = p4r;   // P[wd][h]
    *(bf16x4*)(&Pim[(16*ct + c)*TP + 16*wv + 4*q]) = p4i;
  }
  __syncthreads();
  // ---- step B: A rows wd=16wv+c of P, B rows hd'=16(ct^4)+c ----
  short8 ar[4], ai[4];
  #pragma unroll
  for(int kt=0; kt<4; kt++){
    ar[kt] = *(const short8*)(&Pre[(16*wv + c)*TP + kt*32 + 8*q]);
    ai[kt] = *(const short8*)(&Pim[(16*wv + c)*TP + kt*32 + 8*q]);
  }
  int bp = (b + 8) & 15, cp = (ch + 64) & 127;
  uint* dst = spec + (size_t)(bp*128 + cp)*PLANE;
  const float SC = 1.0f/128.0f;
  uint* tw = ((uint*)scr) + wv*320;            // per-wave 16x16 scratch
  #pragma unroll
  for(int ct=0; ct<8; ct++){
    const uint hiM = (ct<4) ? 0x80000000u : 0u;
    f32x4 sp = {0,0,0,0}, sn = {0,0,0,0}, si = {0,0,0,0};
    #pragma unroll
    for(int kt=0; kt<4; kt++){
      uint m = ((kt>=2)?LM:0u) ^ hiM;
      short8 br = frg(st_r[ct&3][kt&1], m);
      short8 bi = frg(st_i[ct&3][kt&1], m);
      sp = __builtin_amdgcn_mfma_f32_16x16x32_bf16(ar[kt], br, sp, 0,0,0);
      sn = __builtin_amdgcn_mfma_f32_16x16x32_bf16(ai[kt], bi, sn, 0,0,0);
      si = __builtin_amdgcn_mfma_f32_16x16x32_bf16(ar[kt], bi, si, 0,0,0);
      si = __builtin_amdgcn_mfma_f32_16x16x32_bf16(ai[kt], br, si, 0,0,0);
    }
    int hd0 = 16*ct;
    {
      int hd = hd0 + c;
      float dh = (float)hd - 63.5f;
      float dh2 = dh*dh;
      #pragma unroll
      for(int r=0; r<4; r++){
        int wd = 16*wv + 4*q + r;
        float dw = (float)wd - 63.5f;
        float mm = (dw*dw + dh2 >= 64.0f) ? SC : 0.0f;
        tw[(4*q+r)*16 + c] = pk((sp[r]-sn[r])*mm, si[r]*mm);
      }
    }
    u32x4 v4 = *(u32x4*)(tw + (l>>2)*16 + (l&3)*4);
    *(u32x4*)(dst + (16*wv + (l>>2))*128 + hd0 + (l&3)*4) = v4;
  }
}

// ---------------- kernel 2: fused 1x1conv chain via bf16 MFMA ----------------
#define XPITCH 136
#define EPITCH 264
__global__ __launch_bounds__(256,3) void k_conv(const float* __restrict__ wb,
                                                const uint* __restrict__ spec,
                                                uint* __restrict__ zo){
  __shared__ ushort xs[64*XPITCH];
  __shared__ ushort hs[64*EPITCH];
  const ushort* wbs = (const ushort*)wb;
  int bid = blockIdx.x;
  int b = bid >> 9;
  int pix0 = (bid & 511) * 32;
  const uint* sp = spec + (size_t)(b*128)*PLANE + pix0;
  int t = threadIdx.x, l = t & 63, w = t >> 6;
  {
    int p = t & 31, g = t >> 5;
    #pragma unroll
    for(int half=0; half<2; half++){
      ushort re8[8], im8[8];
      #pragma unroll
      for(int k=0;k<8;k++){
        uint u = sp[(size_t)(g*16 + half*8 + k)*PLANE + p];
        re8[k] = (ushort)u; im8[k] = (ushort)(u>>16);
      }
      *(ushort8*)(xs + p*XPITCH      + g*16 + half*8) = *(ushort8*)re8;
      *(ushort8*)(xs + (p+32)*XPITCH + g*16 + half*8) = *(ushort8*)im8;
    }
  }
  short8 bw1[4][4];
  #pragma unroll
  for(int et=0; et<4; et++)
    #pragma unroll
    for(int kt=0; kt<4; kt++)
      bw1[et][kt] = *(const short8*)(wbs + (((w*4+et)*4 + kt)*64 + l)*8);
  float c1v[4];
  #pragma unroll
  for(int et=0; et<4; et++) c1v[et] = wb[32768 + w*64 + et*16 + (l&15)];
  __syncthreads();
  #pragma unroll
  for(int mt=0; mt<4; mt++){
    short8 xa[4];
    #pragma unroll
    for(int kt=0; kt<4; kt++)
      xa[kt] = *(const short8*)(xs + (mt*16 + (l&15))*XPITCH + kt*32 + 8*(l>>4));
    f32x4 a0 = {0,0,0,0}, a1 = {0,0,0,0}, a2 = {0,0,0,0}, a3 = {0,0,0,0};
    #pragma unroll
    for(int kt=0; kt<4; kt++){
      a0 = __builtin_amdgcn_mfma_f32_16x16x32_bf16(xa[kt], bw1[0][kt], a0, 0,0,0);
      a1 = __builtin_amdgcn_mfma_f32_16x16x32_bf16(xa[kt], bw1[1][kt], a1, 0,0,0);
      a2 = __builtin_amdgcn_mfma_f32_16x16x32_bf16(xa[kt], bw1[2][kt], a2, 0,0,0);
      a3 = __builtin_amdgcn_mfma_f32_16x16x32_bf16(xa[kt], bw1[3][kt], a3, 0,0,0);
    }
    #pragma unroll
    for(int et=0; et<4; et++){
      f32x4 av = et==0?a0 : et==1?a1 : et==2?a2 : a3;
      #pragma unroll
      for(int r=0; r<4; r++){
        float h = fmaxf(av[r] + c1v[et], 0.f);
        hs[(mt*16 + (l>>4)*4 + r)*EPITCH + w*64 + et*16 + (l&15)] = f2bf(h);
      }
    }
  }
  short8 aw2[2][8];
  #pragma unroll
  for(int ot=0; ot<2; ot++)
    #pragma unroll
    for(int kt=0; kt<8; kt++)
      aw2[ot][kt] = *(const short8*)(wbs + 32768 + (((w*2+ot)*8 + kt)*64 + l)*8);
  float c2r[8];
  #pragma unroll
  for(int ot=0; ot<2; ot++)
    #pragma unroll
    for(int r=0; r<4; r++)
      c2r[ot*4+r] = wb[33024 + w*32 + ot*16 + (l>>4)*4 + r];
  __syncthreads();
  f32x4 d[2][4];
  #pragma unroll
  for(int ot=0; ot<2; ot++)
    #pragma unroll
    for(int pt=0; pt<4; pt++) d[ot][pt] = (f32x4){0,0,0,0};
  for(int kt=0; kt<8; kt++){
    short8 hb[4];
    #pragma unroll
    for(int pt=0; pt<4; pt++)
      hb[pt] = *(const short8*)(hs + (pt*16 + (l&15))*EPITCH + kt*32 + 8*(l>>4));
    #pragma unroll
    for(int ot=0; ot<2; ot++)
      #pragma unroll
      for(int pt=0; pt<4; pt++)
        d[ot][pt] = __builtin_amdgcn_mfma_f32_16x16x32_bf16(aw2[ot][kt], hb[pt], d[ot][pt], 0,0,0);
  }
  uint* zb = zo + (size_t)(b*128)*PLANE + pix0;
  #pragma unroll
  for(int ot=0; ot<2; ot++){
    #pragma unroll
    for(int pp=0; pp<2; pp++){
      #pragma unroll
      for(int r=0; r<4; r++){
        int o = w*32 + ot*16 + (l>>4)*4 + r;
        int p = pp*16 + (l&15);
        float re = d[ot][pp][r]   + c2r[ot*4+r] + bf2f(xs[p*XPITCH + o]);
        float im = d[ot][pp+2][r] + c2r[ot*4+r] + bf2f(xs[(p+32)*XPITCH + o]);
        zb[(size_t)o*PLANE + p] = pk(re, im);
      }
    }
  }
}

// ---------------- kernel 3: inverse 2D DFT via MFMA + |.| + outputs ----------
// 1 blk/CU (LDS-padded). z[wd][hd] bf16 packed (aliases out+2*NTOT).
// Step A: T[nh][wd] = sum_hd Z[wd][hd]*G[nh][hd]  (rows 16wv+c read once)
// Step B: S[nh][nw] = sum_wd T[nh][wd]*G[nw][wd]; h=|S|/128; per-ct
//         interleaved transposed epilogue (R6-proven clean store pattern).
__global__ __launch_bounds__(512,1) void k_ifft_out(const uint* z,
                                                    const float* __restrict__ xin1,
                                                    const float* __restrict__ xin2,
                                                    float* out){
  __shared__ ushort Tre[128*TP], Tim[128*TP];   // T stored [nh][wd]
  __shared__ ushort scr[8*640 + 10240];         // wave scratch + pad -> 1 blk/CU
  int t = threadIdx.x, l = t & 63, wv = t >> 6, c = l & 15, q = l >> 4;
  int bid = blockIdx.x, b = bid >> 7, o = bid & 127;
  size_t plane = (size_t)(b*128 + o)*PLANE;
  const uint* zp = z + plane;
  short8 st_r[4][2], st_i[4][2];
  gen_quarter<1>(st_r, st_i, c, q);
  uint LM = (c&1) ? 0x80008000u : 0u;
  // ---- step A: A rows wd=16wv+c of z (read once), B rows nh=16ct+c ----
  short8 zr[4], zi[4];
  #pragma unroll
  for(int kt=0; kt<4; kt++){
    const uint* ap = zp + (16*wv + c)*128 + kt*32 + 8*q;
    unpack2(*(const u32x4*)ap, *(const u32x4*)(ap+4), zr[kt], zi[kt]);
  }
  #pragma unroll
  for(int ct=0; ct<8; ct++){
    const uint hiM = (ct>=4) ? 0x80000000u : 0u;
    f32x4 tp = {0,0,0,0}, tn = {0,0,0,0}, ti = {0,0,0,0};
    #pragma unroll
    for(int kt=0; kt<4; kt++){
      uint m = ((kt>=2)?LM:0u) ^ hiM;
      short8 br = frg(st_r[ct&3][kt&1], m);
      short8 bi = frg(st_i[ct&3][kt&1], m);
      tp = __builtin_amdgcn_mfma_f32_16x16x32_bf16(zr[kt], br, tp, 0,0,0);
      tn = __builtin_amdgcn_mfma_f32_16x16x32_bf16(zi[kt], bi, tn, 0,0,0);
      ti = __builtin_amdgcn_mfma_f32_16x16x32_bf16(zr[kt], bi, ti, 0,0,0);
      ti = __builtin_amdgcn_mfma_f32_16x16x32_bf16(zi[kt], br, ti, 0,0,0);
    }
    bf16x4 t4r, t4i;
    #pragma unroll
    for(int r=0;r<4;r++){ t4r[r]=f2bf(tp[r]-tn[r]); t4i[r]=f2bf(ti[r]); }
    *(bf16x4*)(&Tre[(16*ct + c)*TP + 16*wv + 4*q]) = t4r;   // T[nh][wd]
    *(bf16x4*)(&Tim[(16*ct + c)*TP + 16*wv + 4*q]) = t4i;
  }
  __syncthreads();     // all z reads (aliasing hx) complete before any out write
  // ---- step B: A rows nh=16wv+c of T, B rows nw=16ct+c ----
  short8 ar[4], ai[4];
  #pragma unroll
  for(int kt=0; kt<4; kt++){
    ar[kt] = *(const short8*)(&Tre[(16*wv + c)*TP + kt*32 + 8*q]);
    ai[kt] = *(const short8*)(&Tim[(16*wv + c)*TP + kt*32 + 8*q]);
  }
  const float SC = 1.0f/128.0f;
  float* hw = ((float*)scr) + wv*320;          // per-wave 16x20 f32 scratch
  #pragma unroll
  for(int ct=0; ct<8; ct++){
    const uint hiM = (ct>=4) ? 0x80000000u : 0u;
    f32x4 sp = {0,0,0,0}, sn = {0,0,0,0}, si = {0,0,0,0};
    #pragma unroll
    for(int kt=0; kt<4; kt++){
      uint m = ((kt>=2)?LM:0u) ^ hiM;
      short8 br = frg(st_r[ct&3][kt&1], m);
      short8 bi = frg(st_i[ct&3][kt&1], m);
      sp = __builtin_amdgcn_mfma_f32_16x16x32_bf16(ar[kt], br, sp, 0,0,0);
      sn = __builtin_amdgcn_mfma_f32_16x16x32_bf16(ai[kt], bi, sn, 0,0,0);
      si = __builtin_amdgcn_mfma_f32_16x16x32_bf16(ar[kt], bi, si, 0,0,0);
      si = __builtin_amdgcn_mfma_f32_16x16x32_bf16(ai[kt], br, si, 0,0,0);
    }
    #pragma unroll
    for(int r=0; r<4; r++){
      float re = sp[r]-sn[r], im = si[r];
      hw[(4*q+r)*20 + c] = sqrtf(re*re + im*im) * SC;
    }
    f32x4 h4 = *(f32x4*)(hw + (l>>2)*20 + (l&3)*4);
    size_t idx4 = plane + (size_t)(16*wv + (l>>2))*128 + 16*ct + (l&3)*4;
    f32x4 u = *(const f32x4*)(xin1 + idx4);
    f32x4 v = *(const f32x4*)(xin2 + idx4);
    f32x4 o1, o2;
    #pragma unroll
    for(int j=0;j<4;j++){ o1[j] = u[j]*h4[j] + u[j]; o2[j] = v[j]*h4[j] + v[j]; }
    *(f32x4*)(out + idx4) = o1;
    *(f32x4*)(out + NTOT + idx4) = o2;
    *(f32x4*)(out + 2u*NTOT + idx4) = h4;
  }
}

extern "C" void kernel_launch(void* const* d_in, const int* in_sizes, int n_in,
                              void* d_out, int out_size, void* d_ws, size_t ws_size,
                              hipStream_t stream){
  (void)in_sizes; (void)n_in; (void)d_ws; (void)ws_size; (void)out_size;
  const float* x1  = (const float*)d_in[0];
  const float* x2  = (const float*)d_in[1];
  const float* w1  = (const float*)d_in[2];
  const float* b1  = (const float*)d_in[3];
  const float* g1  = (const float*)d_in[4];
  const float* be1 = (const float*)d_in[5];
  const float* m1  = (const float*)d_in[6];
  const float* v1  = (const float*)d_in[7];
  const float* w2  = (const float*)d_in[8];
  const float* b2  = (const float*)d_in[9];
  const float* g2  = (const float*)d_in[10];
  const float* be2 = (const float*)d_in[11];
  const float* m2  = (const float*)d_in[12];
  const float* v2  = (const float*)d_in[13];
  float* out = (float*)d_out;
  float* wb   = out;                       // slot0: weights (dead after conv)
  uint*  spec = (uint*)(out + NTOT);       // slot1: bf16 spectrum (dead after conv)
  uint*  z    = (uint*)(out + 2u*NTOT);    // slot2: bf16 z, plane-aliased with hx
  hipLaunchKernelGGL(k_prep,     dim3(256),  dim3(256), 0, stream,
                     w1,b1,g1,be1,m1,v1,w2,b2,g2,be2,m2,v2, wb);
  hipLaunchKernelGGL(k_fft_fwd,  dim3(2048), dim3(512), 0, stream, x2, spec);
  hipLaunchKernelGGL(k_conv,     dim3(8192), dim3(256), 0, stream, wb, spec, z);
  hipLaunchKernelGGL(k_ifft_out, dim3(2048), dim3(512), 0, stream, z, x1, x2, out);
}